// Round 18
// baseline (277.467 us; speedup 1.0000x reference)
//
#include <hip/hip_runtime.h>

typedef unsigned short u16;
typedef unsigned int u32;
typedef __bf16 bf16x8 __attribute__((ext_vector_type(8)));
typedef float f32x4 __attribute__((ext_vector_type(4)));

#define B_ROWS 16384
#define K1 1536

__device__ __forceinline__ u16 f2bf(float f) {
  u32 u = __float_as_uint(f);
  u = (u + 0x7fffu + ((u >> 16) & 1u)) >> 16;  // RNE
  return (u16)u;
}
__device__ __forceinline__ float bf2f(u16 b) {
  return __uint_as_float(((u32)b) << 16);
}
__device__ __forceinline__ void gload_lds16(const void* g, void* l) {
  __builtin_amdgcn_global_load_lds((const __attribute__((address_space(1))) void*)g,
                                   (__attribute__((address_space(3))) void*)l,
                                   16, 0, 0);
}

// ---------------- fused prep: xh concat-convert + 6 weight transposes ----------------
__global__ void prep(const float* __restrict__ x, const float* __restrict__ h,
                     u16* __restrict__ xh,
                     const float* __restrict__ Wxr, const float* __restrict__ Whr,
                     const float* __restrict__ Wxz, const float* __restrict__ Whz,
                     const float* __restrict__ Wxh, const float* __restrict__ Whh,
                     u16* __restrict__ W1t, u16* __restrict__ W2t) {
  if (blockIdx.x < 24576) {
    const int iv = blockIdx.x * 256 + threadIdx.x;
    const int row = iv / 384;
    const int col = (iv - row * 384) * 4;
    const float* src = (col < 512) ? x + (size_t)row * 512 + col
                                   : h + (size_t)row * 1024 + (col - 512);
    float4 v = *(const float4*)src;
    u32 a = (u32)f2bf(v.x) | ((u32)f2bf(v.y) << 16);
    u32 b = (u32)f2bf(v.z) | ((u32)f2bf(v.w) << 16);
    *(uint2*)(xh + (size_t)row * 1536 + col) = make_uint2(a, b);
    return;
  }
  __shared__ float tile[32][33];
  const int idx2 = blockIdx.x - 24576;
  const int z = idx2 >> 10;
  const int rem = idx2 & 1023;
  const int by = rem >> 5, bx = rem & 31;
  const float* W;
  u16* T;
  int Ks, koff, roff;
  switch (z) {
    case 0:  W = Wxr; T = W1t; Ks = 512;  koff = 0;   roff = 0;    break;
    case 1:  W = Whr; T = W1t; Ks = 1024; koff = 512; roff = 0;    break;
    case 2:  W = Wxz; T = W1t; Ks = 512;  koff = 0;   roff = 1024; break;
    case 3:  W = Whz; T = W1t; Ks = 1024; koff = 512; roff = 1024; break;
    case 4:  W = Wxh; T = W2t; Ks = 512;  koff = 0;   roff = 0;    break;
    default: W = Whh; T = W2t; Ks = 1024; koff = 512; roff = 0;    break;
  }
  if (by * 32 >= Ks) return;
  const int tx = threadIdx.x & 31, ty = threadIdx.x >> 5;
#pragma unroll
  for (int r = 0; r < 32; r += 8)
    tile[ty + r][tx] = W[(size_t)(by * 32 + ty + r) * 1024 + bx * 32 + tx];
  __syncthreads();
#pragma unroll
  for (int r = 0; r < 32; r += 8)
    T[(size_t)(roff + bx * 32 + ty + r) * K1 + koff + by * 32 + tx] = f2bf(tile[tx][ty + r]);
}

// ---------------- shared 256x128 dbuf 4-phase core (R13-verified G2 structure) ----------
// 8 waves as 4M x 2N (64x64 each); 6 gload_lds/tile; A01(t+2)@ph3, A23(t+1)@ph0,
// B(t+1)@ph1; vmcnt(2) ledger verified in R13. A optionally rebases at tsw.
struct CoreArgs {
  const u16 *A, *A2, *B;
  u32 sA, sA2, sB;
  int tsw;  // tile where A switches to A2 (k restarts); <0 disables
};

__device__ __forceinline__ void core256x128(const CoreArgs& C, int brow, int bcolB,
                                            u16* AsU, u16* BsU, f32x4 acc[4][4]) {
  const int tid = threadIdx.x;
  const int l = tid & 63;
  const int wid = tid >> 6;
  const int lr = l & 15, kq = l >> 4;
  const int wrk = wid >> 1, wc = wid & 1;
  const int swzB = (lr & 7) * 16;
  const int kswzE = ((tid & 7) ^ ((tid >> 3) & 7)) * 8;
  const int r = tid >> 3;
  char* AsB = (char*)AsU;
  char* BsB = (char*)BsU;
  const int ldsQ = wid << 10;
  const int colK0 = (kq * 16) ^ swzB;
  const int colK1 = (64 + kq * 16) ^ swzB;
  int aRow[4], bRow[4];
#pragma unroll
  for (int m = 0; m < 4; ++m) aRow[m] = (wrk * 64 + m * 16 + lr) * 128;
#pragma unroll
  for (int n = 0; n < 4; ++n) bRow[n] = (wc * 64 + n * 16 + lr) * 128;

  const u16* pA01 = C.A;
  const u16* pA23 = C.A;
  u32 offA[4], offB[2];
#pragma unroll
  for (int q = 0; q < 4; ++q) offA[q] = (u32)((brow + q * 64 + r) * C.sA + kswzE) * 2u;
#pragma unroll
  for (int q = 0; q < 2; ++q) offB[q] = (u32)((bcolB + q * 64 + r) * C.sB + kswzE) * 2u;

#define C_A01(q_, c_) gload_lds16((const char*)pA01 + offA[q_], \
    AsB + (c_) * 32768 + (q_) * 8192 + ldsQ)
#define C_A23(q_, c_) gload_lds16((const char*)pA23 + offA[q_], \
    AsB + (c_) * 32768 + 16384 + ((q_) - 2) * 8192 + ldsQ)
#define C_B(q_, c_)   gload_lds16((const char*)C.B + offB[q_], \
    BsB + (c_) * 16384 + (q_) * 8192 + ldsQ)

  // prologue: tile0 (6 loads) + tile1 A01 (2) -> vmcnt(2)
  C_A01(0, 0); C_A01(1, 0);
  C_A23(2, 0); C_A23(3, 0);
  C_B(0, 0); C_B(1, 0);
  offA[0] += 128; offA[1] += 128;
  C_A01(0, 1); C_A01(1, 1);
  offA[0] += 128; offA[1] += 128;
  offA[2] += 128; offA[3] += 128;
  offB[0] += 128; offB[1] += 128;
  asm volatile("s_waitcnt vmcnt(2)" ::: "memory");
  __builtin_amdgcn_s_barrier();
  asm volatile("" ::: "memory");

  const int nt = 24;
  for (int t = 0; t < nt; ++t) {
    const int c = t & 1;
    const int cbA = c << 15;
    const int cbB = c << 14;
    bf16x8 a01[2][2], a23[2][2], b01[2][2], b23[2][2];
    // ph0: read a01+b01; stage A23(t+1); MFMA q00
#pragma unroll
    for (int m = 0; m < 2; ++m) {
      a01[m][0] = *(const bf16x8*)(AsB + cbA + aRow[m] + colK0);
      a01[m][1] = *(const bf16x8*)(AsB + cbA + aRow[m] + colK1);
    }
#pragma unroll
    for (int n = 0; n < 2; ++n) {
      b01[n][0] = *(const bf16x8*)(BsB + cbB + bRow[n] + colK0);
      b01[n][1] = *(const bf16x8*)(BsB + cbB + bRow[n] + colK1);
    }
    if (t + 1 < nt) { C_A23(2, c ^ 1); C_A23(3, c ^ 1); }
    __builtin_amdgcn_s_barrier();
    asm volatile("s_waitcnt lgkmcnt(0)" ::: "memory");
    __builtin_amdgcn_sched_barrier(0);
    __builtin_amdgcn_s_setprio(1);
#pragma unroll
    for (int kk = 0; kk < 2; ++kk)
#pragma unroll
      for (int m = 0; m < 2; ++m)
#pragma unroll
        for (int n = 0; n < 2; ++n)
          acc[m][n] = __builtin_amdgcn_mfma_f32_16x16x32_bf16(a01[m][kk], b01[n][kk], acc[m][n], 0, 0, 0);
    __builtin_amdgcn_s_setprio(0);
    __builtin_amdgcn_s_barrier();
    asm volatile("" ::: "memory");
    // ph1: read b23; stage B(t+1); MFMA q01
#pragma unroll
    for (int n = 0; n < 2; ++n) {
      b23[n][0] = *(const bf16x8*)(BsB + cbB + bRow[n + 2] + colK0);
      b23[n][1] = *(const bf16x8*)(BsB + cbB + bRow[n + 2] + colK1);
    }
    if (t + 1 < nt) { C_B(0, c ^ 1); C_B(1, c ^ 1); }
    __builtin_amdgcn_s_barrier();
    asm volatile("s_waitcnt lgkmcnt(0)" ::: "memory");
    __builtin_amdgcn_sched_barrier(0);
    __builtin_amdgcn_s_setprio(1);
#pragma unroll
    for (int kk = 0; kk < 2; ++kk)
#pragma unroll
      for (int m = 0; m < 2; ++m)
#pragma unroll
        for (int n = 0; n < 2; ++n)
          acc[m][n + 2] = __builtin_amdgcn_mfma_f32_16x16x32_bf16(a01[m][kk], b23[n][kk], acc[m][n + 2], 0, 0, 0);
    __builtin_amdgcn_s_setprio(0);
    __builtin_amdgcn_s_barrier();
    asm volatile("" ::: "memory");
    // ph2: read a23; MFMA q11
#pragma unroll
    for (int m = 0; m < 2; ++m) {
      a23[m][0] = *(const bf16x8*)(AsB + cbA + aRow[m + 2] + colK0);
      a23[m][1] = *(const bf16x8*)(AsB + cbA + aRow[m + 2] + colK1);
    }
    __builtin_amdgcn_s_barrier();
    asm volatile("s_waitcnt lgkmcnt(0)" ::: "memory");
    __builtin_amdgcn_sched_barrier(0);
    __builtin_amdgcn_s_setprio(1);
#pragma unroll
    for (int kk = 0; kk < 2; ++kk)
#pragma unroll
      for (int m = 0; m < 2; ++m)
#pragma unroll
        for (int n = 0; n < 2; ++n)
          acc[m + 2][n + 2] = __builtin_amdgcn_mfma_f32_16x16x32_bf16(a23[m][kk], b23[n][kk], acc[m + 2][n + 2], 0, 0, 0);
    __builtin_amdgcn_s_setprio(0);
    __builtin_amdgcn_s_barrier();
    asm volatile("" ::: "memory");
    // ph3: stage A01(t+2); MFMA q10; counted vmcnt
    if (t + 2 < nt) { C_A01(0, c); C_A01(1, c); }
    __builtin_amdgcn_s_barrier();
    __builtin_amdgcn_s_setprio(1);
#pragma unroll
    for (int kk = 0; kk < 2; ++kk)
#pragma unroll
      for (int m = 0; m < 2; ++m)
#pragma unroll
        for (int n = 0; n < 2; ++n)
          acc[m + 2][n] = __builtin_amdgcn_mfma_f32_16x16x32_bf16(a23[m][kk], b01[n][kk], acc[m + 2][n], 0, 0, 0);
    __builtin_amdgcn_s_setprio(0);
    if (t + 2 < nt) { asm volatile("s_waitcnt vmcnt(2)" ::: "memory"); }
    else            { asm volatile("s_waitcnt vmcnt(0)" ::: "memory"); }
    __builtin_amdgcn_s_barrier();
    asm volatile("" ::: "memory");
    // advance / optional A rebase (staged ahead: A01 at tsw-3, A23 at tsw-2)
    if (t == C.tsw - 3) {
      pA01 = C.A2;
      offA[0] = (u32)((brow + 0 * 64 + r) * C.sA2 + kswzE) * 2u;
      offA[1] = (u32)((brow + 1 * 64 + r) * C.sA2 + kswzE) * 2u;
    } else { offA[0] += 128; offA[1] += 128; }
    if (t == C.tsw - 2) {
      pA23 = C.A2;
      offA[2] = (u32)((brow + 2 * 64 + r) * C.sA2 + kswzE) * 2u;
      offA[3] = (u32)((brow + 3 * 64 + r) * C.sA2 + kswzE) * 2u;
    } else { offA[2] += 128; offA[3] += 128; }
    offB[0] += 128; offB[1] += 128;
  }
#undef C_A01
#undef C_A23
#undef C_B
}

// ---------------- GEMM1 (R18): 256x128 tiles, 1024 blocks = 4 rounds ----------------
// Round-overlap mechanism (R13 win): round-k epilogue/prologue hides under
// round-k+1 compute. A-panels staged 2x vs R14 (slack HBM absorbs it).
__global__ __launch_bounds__(512, 1) void gru_gemm1(
    const u16* __restrict__ xh, const u16* __restrict__ W1t,
    const float* __restrict__ bxr, const float* __restrict__ bxz,
    u16* __restrict__ rhb, u16* __restrict__ zb) {
  __shared__ __align__(16) u16 As[2 * 256 * 64];   // 64 KB
  __shared__ __align__(16) u16 Bs[2 * 128 * 64];   // 32 KB
  const int orig = blockIdx.x;                  // 1024 blocks
  const int slot = orig >> 3;                   // 0..127
  const int jt = slot & 15;                     // 0..15 (N=2048)
  const int mt = (orig & 7) + 8 * (slot >> 4);  // 0..63; 16 same-XCD slots share A panel
  const int brow = mt * 256;

  CoreArgs C { xh, xh, W1t, K1, K1, K1, -100 };
  f32x4 acc[4][4] = {};
  core256x128(C, brow, jt * 128, As, Bs, acc);

  const int l = threadIdx.x & 63;
  const int wid = threadIdx.x >> 6;
  const int wrk = wid >> 1, wc = wid & 1;
  const int colb = (jt & 7) * 128 + wc * 64 + (l & 15);  // within 1024
  const int rowb = brow + wrk * 64 + (l >> 4) * 4;
  if (jt < 8) {  // reset gate -> store r*h (bf16)
#pragma unroll
    for (int n = 0; n < 4; ++n) {
      const int col = colb + n * 16;
      const float bias = bxr[col];
#pragma unroll
      for (int m = 0; m < 4; ++m)
#pragma unroll
        for (int j = 0; j < 4; ++j) {
          const int row = rowb + m * 16 + j;
          const float rg = 1.f / (1.f + __expf(-(acc[m][n][j] + bias)));
          const float hv = bf2f(xh[(size_t)row * K1 + 512 + col]);
          rhb[(size_t)row * 1024 + col] = f2bf(rg * hv);
        }
    }
  } else {  // update gate -> store z (bf16)
#pragma unroll
    for (int n = 0; n < 4; ++n) {
      const int col = colb + n * 16;
      const float bias = bxz[col];
#pragma unroll
      for (int m = 0; m < 4; ++m)
#pragma unroll
        for (int j = 0; j < 4; ++j) {
          const int row = rowb + m * 16 + j;
          const float zg = 1.f / (1.f + __expf(-(acc[m][n][j] + bias)));
          zb[(size_t)row * 1024 + col] = f2bf(zg);
        }
    }
  }
}

// ---------------- GEMM2 (R13/R17, unchanged): 256x128, 512 blocks, A rebases ----------------
__global__ __launch_bounds__(512, 1) void gru_gemm2(
    const u16* __restrict__ xh, const u16* __restrict__ rhb,
    const u16* __restrict__ W2t, const float* __restrict__ bxh,
    const u16* __restrict__ zb, float* __restrict__ out) {
  __shared__ __align__(16) u16 As[2 * 256 * 64];   // 64 KB
  __shared__ __align__(16) u16 Bs[2 * 128 * 64];   // 32 KB
  const int orig = blockIdx.x;                   // 512 blocks
  const int wg = (orig & 7) * 64 + (orig >> 3);  // bijective XCD swizzle
  const int mt = wg & 63;                        // mt-fast (R3-style)
  const int jt = wg >> 6;                        // 0..7
  const int brow = mt * 256;
  const int jcol = jt * 128;

  CoreArgs C { xh, rhb, W2t, K1, 1024, K1, 8 };  // A rebases xh->rhb at tile 8
  f32x4 acc[4][4] = {};
  core256x128(C, brow, jcol, As, Bs, acc);

  const int l = threadIdx.x & 63;
  const int wid = threadIdx.x >> 6;
  const int wrk = wid >> 1, wc = wid & 1;
  const int colb = jcol + wc * 64 + (l & 15);
  const int rowb = brow + wrk * 64 + (l >> 4) * 4;
#pragma unroll
  for (int n = 0; n < 4; ++n) {
    const int col = colb + n * 16;
    const float bias = bxh[col];
#pragma unroll
    for (int m = 0; m < 4; ++m)
#pragma unroll
      for (int j = 0; j < 4; ++j) {
        const int row = rowb + m * 16 + j;
        const size_t idx = (size_t)row * 1024 + col;
        const float e = __expf(2.f * (acc[m][n][j] + bias));
        const float hc = 1.f - 2.f / (e + 1.f);
        const float z = bf2f(zb[idx]);
        const float h = bf2f(xh[(size_t)row * K1 + 512 + col]);
        out[idx] = z * h + (1.f - z) * hc;
      }
  }
}

extern "C" void kernel_launch(void* const* d_in, const int* in_sizes, int n_in,
                              void* d_out, int out_size, void* d_ws, size_t ws_size,
                              hipStream_t stream) {
  const float* x      = (const float*)d_in[0];
  const float* hidden = (const float*)d_in[1];
  const float* Wxr = (const float*)d_in[2];
  const float* bxr = (const float*)d_in[3];
  const float* Whr = (const float*)d_in[4];
  const float* Wxz = (const float*)d_in[5];
  const float* bxz = (const float*)d_in[6];
  const float* Whz = (const float*)d_in[7];
  const float* Wxh = (const float*)d_in[8];
  const float* bxh = (const float*)d_in[9];
  const float* Whh = (const float*)d_in[10];
  float* out = (float*)d_out;
  (void)in_sizes; (void)n_in; (void)out_size; (void)ws_size;

  char* p = (char*)d_ws;
  u16* xh  = (u16*)p; p += (size_t)B_ROWS * K1 * 2;
  u16* W1t = (u16*)p; p += (size_t)2048 * K1 * 2;
  u16* W2t = (u16*)p; p += (size_t)1024 * K1 * 2;
  u16* rhb = (u16*)p; p += (size_t)B_ROWS * 1024 * 2;
  u16* zb  = (u16*)p; p += (size_t)B_ROWS * 1024 * 2;

  prep<<<24576 + 6144, 256, 0, stream>>>(x, hidden, xh,
                                         Wxr, Whr, Wxz, Whz, Wxh, Whh, W1t, W2t);
  gru_gemm1<<<1024, 512, 0, stream>>>(xh, W1t, bxr, bxz, rhb, zb);
  gru_gemm2<<<512, 512, 0, stream>>>(xh, rhb, W2t, bxh, zb, out);
}

// Round 19
// 250.829 us; speedup vs baseline: 1.1062x; 1.1062x over previous
//
#include <hip/hip_runtime.h>

typedef unsigned short u16;
typedef unsigned int u32;
typedef __bf16 bf16x8 __attribute__((ext_vector_type(8)));
typedef float f32x4 __attribute__((ext_vector_type(4)));

#define B_ROWS 16384
#define K1 1536

__device__ __forceinline__ u16 f2bf(float f) {
  u32 u = __float_as_uint(f);
  u = (u + 0x7fffu + ((u >> 16) & 1u)) >> 16;  // RNE
  return (u16)u;
}
__device__ __forceinline__ float bf2f(u16 b) {
  return __uint_as_float(((u32)b) << 16);
}
__device__ __forceinline__ void gload_lds16(const void* g, void* l) {
  __builtin_amdgcn_global_load_lds((const __attribute__((address_space(1))) void*)g,
                                   (__attribute__((address_space(3))) void*)l,
                                   16, 0, 0);
}

// ---------------- fused prep: xh concat-convert + 6 weight transposes ----------------
__global__ void prep(const float* __restrict__ x, const float* __restrict__ h,
                     u16* __restrict__ xh,
                     const float* __restrict__ Wxr, const float* __restrict__ Whr,
                     const float* __restrict__ Wxz, const float* __restrict__ Whz,
                     const float* __restrict__ Wxh, const float* __restrict__ Whh,
                     u16* __restrict__ W1t, u16* __restrict__ W2t) {
  if (blockIdx.x < 24576) {
    const int iv = blockIdx.x * 256 + threadIdx.x;
    const int row = iv / 384;
    const int col = (iv - row * 384) * 4;
    const float* src = (col < 512) ? x + (size_t)row * 512 + col
                                   : h + (size_t)row * 1024 + (col - 512);
    float4 v = *(const float4*)src;
    u32 a = (u32)f2bf(v.x) | ((u32)f2bf(v.y) << 16);
    u32 b = (u32)f2bf(v.z) | ((u32)f2bf(v.w) << 16);
    *(uint2*)(xh + (size_t)row * 1536 + col) = make_uint2(a, b);
    return;
  }
  __shared__ float tile[32][33];
  const int idx2 = blockIdx.x - 24576;
  const int z = idx2 >> 10;
  const int rem = idx2 & 1023;
  const int by = rem >> 5, bx = rem & 31;
  const float* W;
  u16* T;
  int Ks, koff, roff;
  switch (z) {
    case 0:  W = Wxr; T = W1t; Ks = 512;  koff = 0;   roff = 0;    break;
    case 1:  W = Whr; T = W1t; Ks = 1024; koff = 512; roff = 0;    break;
    case 2:  W = Wxz; T = W1t; Ks = 512;  koff = 0;   roff = 1024; break;
    case 3:  W = Whz; T = W1t; Ks = 1024; koff = 512; roff = 1024; break;
    case 4:  W = Wxh; T = W2t; Ks = 512;  koff = 0;   roff = 0;    break;
    default: W = Whh; T = W2t; Ks = 1024; koff = 512; roff = 0;    break;
  }
  if (by * 32 >= Ks) return;
  const int tx = threadIdx.x & 31, ty = threadIdx.x >> 5;
#pragma unroll
  for (int r = 0; r < 32; r += 8)
    tile[ty + r][tx] = W[(size_t)(by * 32 + ty + r) * 1024 + bx * 32 + tx];
  __syncthreads();
#pragma unroll
  for (int r = 0; r < 32; r += 8)
    T[(size_t)(roff + bx * 32 + ty + r) * K1 + koff + by * 32 + tx] = f2bf(tile[tx][ty + r]);
}

// ---------------- GEMM1 core: 256x256, dbuf, 4-phase (best measured, R10/R14) ----------------
struct Src {
  const u16 *A, *B;
  u32 sA, sB;
};

__device__ __forceinline__ void gemm256(const Src& S, int nt, int brow, int bcol,
                                        u16* AsU, u16* BsU, f32x4 acc[8][4]) {
  const int tid = threadIdx.x;
  const int l = tid & 63;
  const int wid = tid >> 6;
  const int wr = wid >> 2, wc = wid & 3;
  const int lr = l & 15, kq = l >> 4;
  const int swzB = (lr & 7) * 16;
  const int kswzE = ((tid & 7) ^ ((tid >> 3) & 7)) * 8;
  const int r = tid >> 3;
  char* AsB = (char*)AsU;
  char* BsB = (char*)BsU;
  const int ldsQ = wid << 10;
  const int colK0 = (kq * 16) ^ swzB;
  const int colK1 = (64 + kq * 16) ^ swzB;
  int aRow[8], bRow[4];
#pragma unroll
  for (int m = 0; m < 8; ++m) aRow[m] = (wr * 128 + m * 16 + lr) * 128;
#pragma unroll
  for (int n = 0; n < 4; ++n) bRow[n] = (wc * 64 + n * 16 + lr) * 128;

  u32 offA[4], offB[4];
#pragma unroll
  for (int q = 0; q < 4; ++q) {
    offA[q] = (u32)((brow + q * 64 + r) * S.sA + kswzE) * 2u;
    offB[q] = (u32)((bcol + q * 64 + r) * S.sB + kswzE) * 2u;
  }

#define STG_A01(q_, c_) gload_lds16((const char*)S.A + offA[q_], \
    AsB + (c_) * 32768 + (q_) * 8192 + ldsQ)
#define STG_A23(q_, c_) gload_lds16((const char*)S.A + offA[q_], \
    AsB + (c_) * 32768 + 16384 + ((q_) - 2) * 8192 + ldsQ)
#define STG_B(q_, c_)   gload_lds16((const char*)S.B + offB[q_], \
    BsB + (c_) * 32768 + ((q_) >> 1) * 16384 + ((q_) & 1) * 8192 + ldsQ)

  STG_A01(0, 0); STG_A01(1, 0);
  STG_A23(2, 0); STG_A23(3, 0);
  STG_B(0, 0); STG_B(1, 0); STG_B(2, 0); STG_B(3, 0);
  offA[0] += 128; offA[1] += 128;
  STG_A01(0, 1); STG_A01(1, 1);
  offA[0] += 128; offA[1] += 128;
  offA[2] += 128; offA[3] += 128;
  offB[0] += 128; offB[1] += 128; offB[2] += 128; offB[3] += 128;
  asm volatile("s_waitcnt vmcnt(2)" ::: "memory");
  __builtin_amdgcn_s_barrier();
  asm volatile("" ::: "memory");

  for (int t = 0; t < nt; ++t) {
    const int c = t & 1;
    const int cb = c << 15;
    bf16x8 a[4][2], b[4][2];
    // ph0: 12 ds_reads; partial lgkm drain before barrier
#pragma unroll
    for (int m = 0; m < 4; ++m) {
      a[m][0] = *(const bf16x8*)(AsB + cb + aRow[m] + colK0);
      a[m][1] = *(const bf16x8*)(AsB + cb + aRow[m] + colK1);
    }
#pragma unroll
    for (int n = 0; n < 2; ++n) {
      b[n][0] = *(const bf16x8*)(BsB + cb + bRow[n] + colK0);
      b[n][1] = *(const bf16x8*)(BsB + cb + bRow[n] + colK1);
    }
    if (t + 1 < nt) { STG_A23(2, c ^ 1); STG_A23(3, c ^ 1); }
    asm volatile("s_waitcnt lgkmcnt(8)" ::: "memory");
    __builtin_amdgcn_s_barrier();
    asm volatile("s_waitcnt lgkmcnt(0)" ::: "memory");
    __builtin_amdgcn_sched_barrier(0);
    __builtin_amdgcn_s_setprio(1);
#pragma unroll
    for (int kk = 0; kk < 2; ++kk)
#pragma unroll
      for (int m = 0; m < 4; ++m)
#pragma unroll
        for (int n = 0; n < 2; ++n)
          acc[m][n] = __builtin_amdgcn_mfma_f32_16x16x32_bf16(a[m][kk], b[n][kk], acc[m][n], 0, 0, 0);
    __builtin_amdgcn_s_setprio(0);
    __builtin_amdgcn_s_barrier();
    asm volatile("" ::: "memory");
    // ph1
#pragma unroll
    for (int n = 2; n < 4; ++n) {
      b[n][0] = *(const bf16x8*)(BsB + cb + bRow[n] + colK0);
      b[n][1] = *(const bf16x8*)(BsB + cb + bRow[n] + colK1);
    }
    if (t + 1 < nt) { STG_B(0, c ^ 1); STG_B(1, c ^ 1); }
    __builtin_amdgcn_s_barrier();
    asm volatile("s_waitcnt lgkmcnt(0)" ::: "memory");
    __builtin_amdgcn_sched_barrier(0);
    __builtin_amdgcn_s_setprio(1);
#pragma unroll
    for (int kk = 0; kk < 2; ++kk)
#pragma unroll
      for (int m = 0; m < 4; ++m)
#pragma unroll
        for (int n = 2; n < 4; ++n)
          acc[m][n] = __builtin_amdgcn_mfma_f32_16x16x32_bf16(a[m][kk], b[n][kk], acc[m][n], 0, 0, 0);
    __builtin_amdgcn_s_setprio(0);
    __builtin_amdgcn_s_barrier();
    asm volatile("" ::: "memory");
    // ph2
#pragma unroll
    for (int m = 0; m < 4; ++m) {
      a[m][0] = *(const bf16x8*)(AsB + cb + aRow[m + 4] + colK0);
      a[m][1] = *(const bf16x8*)(AsB + cb + aRow[m + 4] + colK1);
    }
    if (t + 1 < nt) { STG_B(2, c ^ 1); STG_B(3, c ^ 1); }
    __builtin_amdgcn_s_barrier();
    asm volatile("s_waitcnt lgkmcnt(0)" ::: "memory");
    __builtin_amdgcn_sched_barrier(0);
    __builtin_amdgcn_s_setprio(1);
#pragma unroll
    for (int kk = 0; kk < 2; ++kk)
#pragma unroll
      for (int m = 0; m < 4; ++m)
#pragma unroll
        for (int n = 2; n < 4; ++n)
          acc[m + 4][n] = __builtin_amdgcn_mfma_f32_16x16x32_bf16(a[m][kk], b[n][kk], acc[m + 4][n], 0, 0, 0);
    __builtin_amdgcn_s_setprio(0);
    __builtin_amdgcn_s_barrier();
    asm volatile("" ::: "memory");
    // ph3
    if (t + 2 < nt) { STG_A01(0, c); STG_A01(1, c); }
    __builtin_amdgcn_s_barrier();
    __builtin_amdgcn_s_setprio(1);
#pragma unroll
    for (int kk = 0; kk < 2; ++kk)
#pragma unroll
      for (int m = 0; m < 4; ++m)
#pragma unroll
        for (int n = 0; n < 2; ++n)
          acc[m + 4][n] = __builtin_amdgcn_mfma_f32_16x16x32_bf16(a[m][kk], b[n][kk], acc[m + 4][n], 0, 0, 0);
    __builtin_amdgcn_s_setprio(0);
    if (t + 2 < nt) { asm volatile("s_waitcnt vmcnt(2)" ::: "memory"); }
    else            { asm volatile("s_waitcnt vmcnt(0)" ::: "memory"); }
    __builtin_amdgcn_s_barrier();
    asm volatile("" ::: "memory");
    offA[0] += 128; offA[1] += 128; offA[2] += 128; offA[3] += 128;
    offB[0] += 128; offB[1] += 128; offB[2] += 128; offB[3] += 128;
  }
#undef STG_A01
#undef STG_A23
#undef STG_B
}

__global__ __launch_bounds__(512, 1) void gru_gemm1(
    const u16* __restrict__ xh, const u16* __restrict__ W1t,
    const float* __restrict__ bxr, const float* __restrict__ bxz,
    u16* __restrict__ rhb, u16* __restrict__ zb) {
  __shared__ __align__(16) u16 As[2 * 256 * 64];
  __shared__ __align__(16) u16 Bs[2 * 256 * 64];
  const int orig = blockIdx.x;                  // 512 blocks
  const int slot = orig >> 3;                   // 0..63
  const int mt = (orig & 7) + 8 * (slot >> 3);  // 0..63
  const int jt = slot & 7;                      // 0..7
  const int brow = mt * 256;
  const int jcol = jt * 256;

  Src S { xh, W1t, K1, K1 };
  f32x4 acc[8][4] = {};
  gemm256(S, 24, brow, jcol, As, Bs, acc);

  const int l = threadIdx.x & 63;
  const int wid = threadIdx.x >> 6;
  const int wr = wid >> 2, wc = wid & 3;
  const int colb = jcol + wc * 64 + (l & 15);
  const int rowb = brow + wr * 128 + (l >> 4) * 4;
  if (jt < 4) {
#pragma unroll
    for (int n = 0; n < 4; ++n) {
      const int col = colb + n * 16;
      const float bias = bxr[col];
#pragma unroll
      for (int m = 0; m < 8; ++m)
#pragma unroll
        for (int j = 0; j < 4; ++j) {
          const int row = rowb + m * 16 + j;
          const float rg = 1.f / (1.f + __expf(-(acc[m][n][j] + bias)));
          const float hv = bf2f(xh[(size_t)row * K1 + 512 + col]);
          rhb[(size_t)row * 1024 + col] = f2bf(rg * hv);
        }
    }
  } else {
#pragma unroll
    for (int n = 0; n < 4; ++n) {
      const int col = colb + n * 16 - 1024;
      const float bias = bxz[col];
#pragma unroll
      for (int m = 0; m < 8; ++m)
#pragma unroll
        for (int j = 0; j < 4; ++j) {
          const int row = rowb + m * 16 + j;
          const float zg = 1.f / (1.f + __expf(-(acc[m][n][j] + bias)));
          zb[(size_t)row * 1024 + col] = f2bf(zg);
        }
    }
  }
}

// ---------------- GEMM2: 256x128 tile, 512 blocks (2 rounds), dbuf 4-phase ----------------
__global__ __launch_bounds__(512, 1) void gru_gemm2(
    const u16* __restrict__ xh, const u16* __restrict__ rhb,
    const u16* __restrict__ W2t, const float* __restrict__ bxh,
    const u16* __restrict__ zb, float* __restrict__ out) {
  __shared__ __align__(16) u16 As[2 * 256 * 64];   // 64 KB
  __shared__ __align__(16) u16 Bs[2 * 128 * 64];   // 32 KB
  const int orig = blockIdx.x;                   // 512 blocks
  const int wg = (orig & 7) * 64 + (orig >> 3);  // bijective XCD swizzle
  const int mt = wg & 63;                        // mt-fast (R3-style)
  const int jt = wg >> 6;                        // 0..7
  const int brow = mt * 256;
  const int jcol = jt * 128;

  const int tid = threadIdx.x;
  const int l = tid & 63;
  const int wid = tid >> 6;
  const int wrk = wid >> 1, wc = wid & 1;
  const int lr = l & 15, kq = l >> 4;
  const int swzB = (lr & 7) * 16;
  const int kswzE = ((tid & 7) ^ ((tid >> 3) & 7)) * 8;
  const int r = tid >> 3;
  char* AsB = (char*)As;
  char* BsB = (char*)Bs;
  const int ldsQ = wid << 10;
  const int colK0 = (kq * 16) ^ swzB;
  const int colK1 = (64 + kq * 16) ^ swzB;
  int aRow[4], bRow[4];
#pragma unroll
  for (int m = 0; m < 4; ++m) aRow[m] = (wrk * 64 + m * 16 + lr) * 128;
#pragma unroll
  for (int n = 0; n < 4; ++n) bRow[n] = (wc * 64 + n * 16 + lr) * 128;

  const u16* pA01 = xh;
  const u16* pA23 = xh;
  u32 offA[4], offB[2];
#pragma unroll
  for (int q = 0; q < 4; ++q) offA[q] = (u32)((brow + q * 64 + r) * K1 + kswzE) * 2u;
#pragma unroll
  for (int q = 0; q < 2; ++q) offB[q] = (u32)((jcol + q * 64 + r) * K1 + kswzE) * 2u;

#define G2_A01(q_, c_) gload_lds16((const char*)pA01 + offA[q_], \
    AsB + (c_) * 32768 + (q_) * 8192 + ldsQ)
#define G2_A23(q_, c_) gload_lds16((const char*)pA23 + offA[q_], \
    AsB + (c_) * 32768 + 16384 + ((q_) - 2) * 8192 + ldsQ)
#define G2_B(q_, c_)   gload_lds16((const char*)W2t + offB[q_], \
    BsB + (c_) * 16384 + (q_) * 8192 + ldsQ)

  G2_A01(0, 0); G2_A01(1, 0);
  G2_A23(2, 0); G2_A23(3, 0);
  G2_B(0, 0); G2_B(1, 0);
  offA[0] += 128; offA[1] += 128;
  G2_A01(0, 1); G2_A01(1, 1);
  offA[0] += 128; offA[1] += 128;
  offA[2] += 128; offA[3] += 128;
  offB[0] += 128; offB[1] += 128;
  asm volatile("s_waitcnt vmcnt(2)" ::: "memory");
  __builtin_amdgcn_s_barrier();
  asm volatile("" ::: "memory");

  f32x4 acc[4][4] = {};
  const int nt = 24;
  for (int t = 0; t < nt; ++t) {
    const int c = t & 1;
    const int cbA = c << 15;
    const int cbB = c << 14;
    bf16x8 a01[2][2], a23[2][2], b01[2][2], b23[2][2];
    // ph0
#pragma unroll
    for (int m = 0; m < 2; ++m) {
      a01[m][0] = *(const bf16x8*)(AsB + cbA + aRow[m] + colK0);
      a01[m][1] = *(const bf16x8*)(AsB + cbA + aRow[m] + colK1);
    }
#pragma unroll
    for (int n = 0; n < 2; ++n) {
      b01[n][0] = *(const bf16x8*)(BsB + cbB + bRow[n] + colK0);
      b01[n][1] = *(const bf16x8*)(BsB + cbB + bRow[n] + colK1);
    }
    if (t + 1 < nt) { G2_A23(2, c ^ 1); G2_A23(3, c ^ 1); }
    __builtin_amdgcn_s_barrier();
    asm volatile("s_waitcnt lgkmcnt(0)" ::: "memory");
    __builtin_amdgcn_sched_barrier(0);
    __builtin_amdgcn_s_setprio(1);
#pragma unroll
    for (int kk = 0; kk < 2; ++kk)
#pragma unroll
      for (int m = 0; m < 2; ++m)
#pragma unroll
        for (int n = 0; n < 2; ++n)
          acc[m][n] = __builtin_amdgcn_mfma_f32_16x16x32_bf16(a01[m][kk], b01[n][kk], acc[m][n], 0, 0, 0);
    __builtin_amdgcn_s_setprio(0);
    __builtin_amdgcn_s_barrier();
    asm volatile("" ::: "memory");
    // ph1
#pragma unroll
    for (int n = 0; n < 2; ++n) {
      b23[n][0] = *(const bf16x8*)(BsB + cbB + bRow[n + 2] + colK0);
      b23[n][1] = *(const bf16x8*)(BsB + cbB + bRow[n + 2] + colK1);
    }
    if (t + 1 < nt) { G2_B(0, c ^ 1); G2_B(1, c ^ 1); }
    __builtin_amdgcn_s_barrier();
    asm volatile("s_waitcnt lgkmcnt(0)" ::: "memory");
    __builtin_amdgcn_sched_barrier(0);
    __builtin_amdgcn_s_setprio(1);
#pragma unroll
    for (int kk = 0; kk < 2; ++kk)
#pragma unroll
      for (int m = 0; m < 2; ++m)
#pragma unroll
        for (int n = 0; n < 2; ++n)
          acc[m][n + 2] = __builtin_amdgcn_mfma_f32_16x16x32_bf16(a01[m][kk], b23[n][kk], acc[m][n + 2], 0, 0, 0);
    __builtin_amdgcn_s_setprio(0);
    __builtin_amdgcn_s_barrier();
    asm volatile("" ::: "memory");
    // ph2
#pragma unroll
    for (int m = 0; m < 2; ++m) {
      a23[m][0] = *(const bf16x8*)(AsB + cbA + aRow[m + 2] + colK0);
      a23[m][1] = *(const bf16x8*)(AsB + cbA + aRow[m + 2] + colK1);
    }
    __builtin_amdgcn_s_barrier();
    asm volatile("s_waitcnt lgkmcnt(0)" ::: "memory");
    __builtin_amdgcn_sched_barrier(0);
    __builtin_amdgcn_s_setprio(1);
#pragma unroll
    for (int kk = 0; kk < 2; ++kk)
#pragma unroll
      for (int m = 0; m < 2; ++m)
#pragma unroll
        for (int n = 0; n < 2; ++n)
          acc[m + 2][n + 2] = __builtin_amdgcn_mfma_f32_16x16x32_bf16(a23[m][kk], b23[n][kk], acc[m + 2][n + 2], 0, 0, 0);
    __builtin_amdgcn_s_setprio(0);
    __builtin_amdgcn_s_barrier();
    asm volatile("" ::: "memory");
    // ph3
    if (t + 2 < nt) { G2_A01(0, c); G2_A01(1, c); }
    __builtin_amdgcn_s_barrier();
    __builtin_amdgcn_s_setprio(1);
#pragma unroll
    for (int kk = 0; kk < 2; ++kk)
#pragma unroll
      for (int m = 0; m < 2; ++m)
#pragma unroll
        for (int n = 0; n < 2; ++n)
          acc[m + 2][n] = __builtin_amdgcn_mfma_f32_16x16x32_bf16(a23[m][kk], b01[n][kk], acc[m + 2][n], 0, 0, 0);
    __builtin_amdgcn_s_setprio(0);
    if (t + 2 < nt) { asm volatile("s_waitcnt vmcnt(2)" ::: "memory"); }
    else            { asm volatile("s_waitcnt vmcnt(0)" ::: "memory"); }
    __builtin_amdgcn_s_barrier();
    asm volatile("" ::: "memory");
    if (t == 5) {
      pA01 = rhb;
      offA[0] = (u32)((brow + 0 * 64 + r) * 1024 + kswzE) * 2u;
      offA[1] = (u32)((brow + 1 * 64 + r) * 1024 + kswzE) * 2u;
    } else { offA[0] += 128; offA[1] += 128; }
    if (t == 6) {
      pA23 = rhb;
      offA[2] = (u32)((brow + 2 * 64 + r) * 1024 + kswzE) * 2u;
      offA[3] = (u32)((brow + 3 * 64 + r) * 1024 + kswzE) * 2u;
    } else { offA[2] += 128; offA[3] += 128; }
    offB[0] += 128; offB[1] += 128;
  }
#undef G2_A01
#undef G2_A23
#undef G2_B

  const int colb = jcol + wc * 64 + (l & 15);
  const int rowb = brow + wrk * 64 + (l >> 4) * 4;
#pragma unroll
  for (int n = 0; n < 4; ++n) {
    const int col = colb + n * 16;
    const float bias = bxh[col];
#pragma unroll
    for (int m = 0; m < 4; ++m)
#pragma unroll
      for (int j = 0; j < 4; ++j) {
        const int row = rowb + m * 16 + j;
        const size_t idx = (size_t)row * 1024 + col;
        const float e = __expf(2.f * (acc[m][n][j] + bias));
        const float hc = 1.f - 2.f / (e + 1.f);
        const float z = bf2f(zb[idx]);
        const float h = bf2f(xh[(size_t)row * K1 + 512 + col]);
        out[idx] = z * h + (1.f - z) * hc;
      }
  }
}

extern "C" void kernel_launch(void* const* d_in, const int* in_sizes, int n_in,
                              void* d_out, int out_size, void* d_ws, size_t ws_size,
                              hipStream_t stream) {
  const float* x      = (const float*)d_in[0];
  const float* hidden = (const float*)d_in[1];
  const float* Wxr = (const float*)d_in[2];
  const float* bxr = (const float*)d_in[3];
  const float* Whr = (const float*)d_in[4];
  const float* Wxz = (const float*)d_in[5];
  const float* bxz = (const float*)d_in[6];
  const float* Whz = (const float*)d_in[7];
  const float* Wxh = (const float*)d_in[8];
  const float* bxh = (const float*)d_in[9];
  const float* Whh = (const float*)d_in[10];
  float* out = (float*)d_out;
  (void)in_sizes; (void)n_in; (void)out_size; (void)ws_size;

  char* p = (char*)d_ws;
  u16* xh  = (u16*)p; p += (size_t)B_ROWS * K1 * 2;
  u16* W1t = (u16*)p; p += (size_t)2048 * K1 * 2;
  u16* W2t = (u16*)p; p += (size_t)1024 * K1 * 2;
  u16* rhb = (u16*)p; p += (size_t)B_ROWS * 1024 * 2;
  u16* zb  = (u16*)p; p += (size_t)B_ROWS * 1024 * 2;

  prep<<<24576 + 6144, 256, 0, stream>>>(x, hidden, xh,
                                         Wxr, Whr, Wxz, Whz, Wxh, Whh, W1t, W2t);
  gru_gemm1<<<512, 512, 0, stream>>>(xh, W1t, bxr, bxz, rhb, zb);
  gru_gemm2<<<512, 512, 0, stream>>>(xh, rhb, W2t, bxh, zb, out);
}